// Round 16
// baseline (3805.545 us; speedup 1.0000x reference)
//
#include <hip/hip_runtime.h>
#include <math.h>

#define NN 8000
#define NE 100000
#define NG 256
#define CC 128
#define NH 4
#define HD 512
#define C3 384
#define HC3 1536
#define NL 5
#define AF 92
#define TE 16
#define TE2 32
#define NEB (NE/TE2)
#define SCALE 0.05103103630798288f

typedef __attribute__((ext_vector_type(8))) __bf16 bf16x8;
typedef __attribute__((ext_vector_type(4))) float f32x4;
typedef __attribute__((ext_vector_type(16))) float f32x16;
typedef __attribute__((ext_vector_type(8))) unsigned short us8;

static __device__ __forceinline__ bf16x8 ldbf8(const unsigned short* p){
  us8 v = *reinterpret_cast<const us8*>(p);
  return __builtin_bit_cast(bf16x8, v);
}
static __device__ __forceinline__ unsigned short f2bf(float f){
  unsigned int u = __builtin_bit_cast(unsigned int, f);
  u += 0x7FFFu + ((u >> 16) & 1u);
  return (unsigned short)(u >> 16);
}
static __device__ __forceinline__ float bf2f(unsigned short u){
  unsigned int x = ((unsigned int)u) << 16;
  return __builtin_bit_cast(float, x);
}
static __device__ __forceinline__ unsigned int packbf(float a, float b){
  return (unsigned int)f2bf(a) | ((unsigned int)f2bf(b) << 16);
}
static __device__ __forceinline__ float sigf(float x){ return 1.0f/(1.0f+__expf(-x)); }
static __device__ __forceinline__ float siluf(float x){ return x/(1.0f+__expf(-x)); }
static __device__ __forceinline__ float softplusf(float x){
  return x > 0.0f ? x + __logf(1.0f+__expf(-x)) : __logf(1.0f+__expf(x));
}
// channel permutation: P (permuted pos in [0,384)) -> original channel j
// tile t=P/32 (0..11), wave w=t/3, part=t%3, row r=P%32 -> j = part*128 + w*32 + r
static __device__ __forceinline__ int permJ(int P){
  int tt = P >> 5;
  int r  = P & 31;
  int w  = tt / 3, part = tt - 3*w;
  return part*128 + w*32 + r;
}

// ================= edge sort by dst (once per call) =================
__global__ void k_hist(const int* __restrict__ dstI, int* __restrict__ cnt){
  int i = blockIdx.x*256 + threadIdx.x;
  if (i < NE) atomicAdd(&cnt[dstI[i]], 1);
}
__global__ __launch_bounds__(1024)
void k_scan(const int* __restrict__ cnt, int* __restrict__ offs, int* __restrict__ cursor){
  __shared__ int a_s[1024], b_s[1024];
  int t = threadIdx.x;
  int base = t*8;
  int v[8]; int s = 0;
  #pragma unroll
  for (int j = 0; j < 8; ++j){
    int c = (base+j < NN) ? cnt[base+j] : 0;
    v[j] = s; s += c;
  }
  a_s[t] = s; __syncthreads();
  int* srcp = a_s; int* dstp = b_s;
  for (int off = 1; off < 1024; off <<= 1){
    int x = srcp[t];
    if (t >= off) x += srcp[t-off];
    dstp[t] = x; __syncthreads();
    int* tmp = srcp; srcp = dstp; dstp = tmp;
  }
  int excl = (t == 0) ? 0 : srcp[t-1];
  #pragma unroll
  for (int j = 0; j < 8; ++j){
    if (base+j < NN){ offs[base+j] = excl + v[j]; cursor[base+j] = excl + v[j]; }
  }
}
__global__ void k_scatter(const int* __restrict__ dstI, int* __restrict__ cursor,
                          int* __restrict__ sperm, int* __restrict__ iperm){
  int i = blockIdx.x*256 + threadIdx.x;
  if (i < NE){
    int d = dstI[i];
    int pos = atomicAdd(&cursor[d], 1);
    sperm[pos] = i;
    iperm[i] = pos;
  }
}
__global__ void k_meta(const int* __restrict__ sperm, const int* __restrict__ srcI,
                       const int* __restrict__ dstI, int* __restrict__ ssrc,
                       int* __restrict__ sdst){
  int i = blockIdx.x*256 + threadIdx.x;
  if (i < NE){ int e = sperm[i]; ssrc[i] = srcI[e]; sdst[i] = dstI[e]; }
}

// ================= weight prep =================
__global__ void k_prep_we(const float* __restrict__ We, unsigned short* __restrict__ WeA){
  size_t i = (size_t)blockIdx.x*256 + threadIdx.x;
  if (i >= (size_t)NL*NH*CC*CC) return;
  int k = i & 127; int r = (i>>7)&127; int hh = (i>>14)&3; int li = (int)(i>>16);
  WeA[i] = f2bf(We[((size_t)li*CC + k)*HD + hh*CC + r]);
}
// WvA rows (768): R<384 -> Pvi row P=R: Wm[k][permJ(P)] ; R>=384 -> Pvj row: Wm[128+k][permJ(P)]
__global__ void k_prep_wv(const float* __restrict__ Wm, unsigned short* __restrict__ WvA){
  size_t i = (size_t)blockIdx.x*256 + threadIdx.x;
  if (i >= (size_t)NL*768*CC) return;
  int k = i & 127; int R = (int)((i>>7) % 768); int li = (int)(i / (768*CC));
  int P = (R < C3) ? R : R - C3;
  int j = permJ(P);
  float val = (R < C3) ? Wm[((size_t)li*C3 + k)*C3 + j]
                       : Wm[((size_t)li*C3 + 128 + k)*C3 + j];
  WvA[i] = f2bf(val);
}
__global__ void k_prep_wg(const float* __restrict__ Wmsg, unsigned short* __restrict__ WgA){
  size_t i = (size_t)blockIdx.x*256 + threadIdx.x;
  if (i >= (size_t)NL*CC*C3) return;
  int P = (int)(i % C3); int c = (int)((i / C3) % CC); int li = (int)(i / ((size_t)CC*C3));
  WgA[i] = f2bf(Wmsg[((size_t)li*C3 + permJ(P))*CC + c]);
}
__global__ __launch_bounds__(128)
void k_prep_wf(const float* __restrict__ We, const float* __restrict__ Wm,
               unsigned short* __restrict__ WfA){
  int b = blockIdx.x;                 // b = ((li*4+hh)*384 + P)
  int P = b % C3; int hh = (b / C3) & 3; int li = b / (C3*NH);
  int o = permJ(P);
  __shared__ float wcol[CC];
  int t = threadIdx.x;
  wcol[t] = Wm[((size_t)li*C3 + 256 + t)*C3 + o];
  __syncthreads();
  const float* werow = We + ((size_t)li*CC + t)*HD + hh*CC;
  float acc = 0.f;
  #pragma unroll 4
  for (int c = 0; c < CC; ++c) acc += werow[c] * wcol[c];
  WfA[(((size_t)li*NH + hh)*C3 + P)*CC + t] = f2bf(acc);
}
// WqkvA[l][m][k]: m<512 -> Wq[l][k][m]; 512..1023 -> Wk; else Wv  (bf16 A-operand)
__global__ void k_prep_wqkv(const float* __restrict__ Wq, const float* __restrict__ Wk,
                            const float* __restrict__ Wv, unsigned short* __restrict__ WA){
  size_t i = (size_t)blockIdx.x*256 + threadIdx.x;
  if (i >= (size_t)NL*1536*CC) return;
  int k = i & 127; int m = (int)((i>>7) % 1536); int li = (int)(i / ((size_t)1536*CC));
  const float* W = (m < 512) ? Wq : (m < 1024) ? Wk : Wv;
  int mm = m & 511;
  WA[i] = f2bf(W[((size_t)li*CC + k)*HD + mm]);
}
// WcA[l][r][k] = Wc[l][k][r]  (bf16 A-operand for k_oc; all layers, once)
__global__ void k_prep_wc(const float* __restrict__ Wc, unsigned short* __restrict__ WcA){
  size_t i = (size_t)blockIdx.x*256 + threadIdx.x;
  if (i >= (size_t)NL*CC*HD) return;
  int k = (int)(i & 511); int r = (int)((i>>9) & 127); int li = (int)(i >> 16);
  WcA[i] = f2bf(Wc[((size_t)li*HD + k)*CC + r]);
}

// ---------------- stem (writes f32 h + bf16 h) ----------------
__global__ __launch_bounds__(128)
void k_stem(const float* __restrict__ x, const float* __restrict__ W,
            const float* __restrict__ b, float* __restrict__ h,
            unsigned short* __restrict__ h_bf){
  __shared__ float xs[8][AF];
  int n0 = blockIdx.x*8;
  int t = threadIdx.x;
  for (int i = t; i < 8*AF; i += 128){ xs[i/AF][i%AF] = x[(size_t)n0*AF + i]; }
  __syncthreads();
  float acc[8] = {};
  for (int f = 0; f < AF; ++f){
    float w = W[f*CC + t];
    #pragma unroll
    for (int n = 0; n < 8; ++n) acc[n] += xs[n][f]*w;
  }
  float bb = b[t];
  #pragma unroll
  for (int n = 0; n < 8; ++n){
    float hv = acc[n] + bb;
    h[(size_t)(n0+n)*CC + t] = hv;
    h_bf[(size_t)(n0+n)*CC + t] = f2bf(hv);
  }
}

// ---------------- rbf MLP -> efs_bf (written directly in SORTED order) ----------------
__global__ __launch_bounds__(128)
void k_rbf(const float* __restrict__ ea, const float* __restrict__ W1, const float* __restrict__ b1,
           const float* __restrict__ W2, const float* __restrict__ b2,
           const int* __restrict__ iperm, unsigned short* __restrict__ efs){
  __shared__ __align__(16) float rs[8][CC];
  __shared__ __align__(16) float ss[8][CC];
  __shared__ float dv[8];
  __shared__ int ip_s[8];
  int e0 = blockIdx.x*8; int t = threadIdx.x;
  if (t < 8){ dv[t] = ea[e0 + t]; ip_s[t] = iperm[e0 + t]; }
  __syncthreads();
  float center = (8.0f/127.0f) * (float)t;
  const float gamma = 15.875f;
  #pragma unroll
  for (int n = 0; n < 8; ++n){ float d = dv[n] - center; rs[n][t] = __expf(-gamma*d*d); }
  __syncthreads();
  {
    float acc[8] = {};
    for (int c0 = 0; c0 < CC; c0 += 4){
      float w0 = W1[(c0+0)*CC+t], w1 = W1[(c0+1)*CC+t], w2 = W1[(c0+2)*CC+t], w3 = W1[(c0+3)*CC+t];
      #pragma unroll
      for (int n = 0; n < 8; ++n){
        float4 r4 = *(const float4*)&rs[n][c0];
        acc[n] += r4.x*w0 + r4.y*w1 + r4.z*w2 + r4.w*w3;
      }
    }
    float bb = b1[t];
    #pragma unroll
    for (int n = 0; n < 8; ++n) ss[n][t] = softplusf(acc[n] + bb);
  }
  __syncthreads();
  {
    float acc[8] = {};
    for (int c0 = 0; c0 < CC; c0 += 4){
      float w0 = W2[(c0+0)*CC+t], w1 = W2[(c0+1)*CC+t], w2 = W2[(c0+2)*CC+t], w3 = W2[(c0+3)*CC+t];
      #pragma unroll
      for (int n = 0; n < 8; ++n){
        float4 r4 = *(const float4*)&ss[n][c0];
        acc[n] += r4.x*w0 + r4.y*w1 + r4.z*w2 + r4.w*w3;
      }
    }
    float bb = b2[t];
    #pragma unroll
    for (int n = 0; n < 8; ++n) efs[(size_t)ip_s[n]*CC + t] = f2bf(acc[n] + bb);
  }
}

// ---------------- q/k/v via 32x32 MFMA (grid: (NN/32, 3)) ----------------
__global__ __launch_bounds__(256)
void k_qkv_mfma(const unsigned short* __restrict__ h_bf,
                const unsigned short* __restrict__ WA,   // [1536][128] this layer
                const float* __restrict__ bq_, const float* __restrict__ bk_,
                const float* __restrict__ bv_,
                unsigned short* __restrict__ qo, unsigned short* __restrict__ ko,
                unsigned short* __restrict__ vo){
  const int t = threadIdx.x;
  const int w = t >> 6, lane = t & 63;
  const int col = lane & 31, hi = lane >> 5;
  const int node = blockIdx.x * 32 + col;
  const int yw = blockIdx.y;   // 0=q, 1=k, 2=v

  const unsigned short* hrow = h_bf + (size_t)node*CC + hi*8;
  bf16x8 bfr[8];
  #pragma unroll
  for (int kc = 0; kc < 8; ++kc) bfr[kc] = ldbf8(hrow + kc*16);

  const float* bias = (yw == 0) ? bq_ : (yw == 1) ? bk_ : bv_;
  unsigned short* outp = (yw == 0) ? qo : (yw == 1) ? ko : vo;
  const unsigned short* Wbase = WA + (size_t)yw*512*CC;

  #pragma unroll
  for (int mt = 0; mt < 4; ++mt){
    f32x16 acc;
    #pragma unroll
    for (int i = 0; i < 16; ++i) acc[i] = 0.f;
    const unsigned short* arow = Wbase + (size_t)(w*128 + mt*32 + col)*CC + hi*8;
    __builtin_amdgcn_s_setprio(1);
    #pragma unroll
    for (int kc = 0; kc < 8; ++kc)
      acc = __builtin_amdgcn_mfma_f32_32x32x16_bf16(ldbf8(arow + kc*16), bfr[kc], acc, 0,0,0);
    __builtin_amdgcn_s_setprio(0);
    #pragma unroll
    for (int g = 0; g < 4; ++g){
      int cb = w*128 + mt*32 + 8*g + 4*hi;
      float4 bb = *(const float4*)(bias + cb);
      uint2 uv;
      uv.x = packbf(acc[4*g+0]+bb.x, acc[4*g+1]+bb.y);
      uv.y = packbf(acc[4*g+2]+bb.z, acc[4*g+3]+bb.w);
      *(uint2*)(outp + (size_t)node*HD + cb) = uv;
    }
  }
}

// ---------------- Pvi/Pvj via 32x32 MFMA (grid: (NN/32, NH)) ----------------
__global__ __launch_bounds__(256)
void k_pv_mfma(const unsigned short* __restrict__ v_bf, const unsigned short* __restrict__ WvA,
               const float* __restrict__ bm,
               unsigned short* __restrict__ Pvi, unsigned short* __restrict__ Pvj){
  const int t = threadIdx.x;
  const int w = t >> 6, lane = t & 63;
  const int col = lane & 31, hi = lane >> 5;
  const int node = blockIdx.x * 32 + col;
  const int h = blockIdx.y;

  const unsigned short* vrow = v_bf + (size_t)node*HD + h*CC + hi*8;
  bf16x8 bfr[8];
  #pragma unroll
  for (int kc = 0; kc < 8; ++kc) bfr[kc] = ldbf8(vrow + kc*16);

  #pragma unroll
  for (int mt = 0; mt < 6; ++mt){
    f32x16 acc;
    #pragma unroll
    for (int i = 0; i < 16; ++i) acc[i] = 0.f;
    int R0 = w*192 + mt*32;                 // tile rows [R0, R0+32) — pure Pvi or pure Pvj
    const unsigned short* arow = WvA + (size_t)(R0 + col)*CC + hi*8;
    __builtin_amdgcn_s_setprio(1);
    #pragma unroll
    for (int kc = 0; kc < 8; ++kc)
      acc = __builtin_amdgcn_mfma_f32_32x32x16_bf16(ldbf8(arow + kc*16), bfr[kc], acc, 0,0,0);
    __builtin_amdgcn_s_setprio(0);
    if (R0 < C3){
      #pragma unroll
      for (int g = 0; g < 4; ++g){
        int P0 = R0 + 8*g + 4*hi;
        int j0 = permJ(P0);                 // 4 consecutive j's
        float4 bq = *(const float4*)(bm + j0);
        uint2 uv;
        uv.x = packbf(acc[4*g+0]+bq.x, acc[4*g+1]+bq.y);
        uv.y = packbf(acc[4*g+2]+bq.z, acc[4*g+3]+bq.w);
        *(uint2*)(Pvi + (size_t)node*HC3 + h*C3 + P0) = uv;
      }
    } else {
      #pragma unroll
      for (int g = 0; g < 4; ++g){
        int P0 = R0 - C3 + 8*g + 4*hi;
        uint2 uv;
        uv.x = packbf(acc[4*g+0], acc[4*g+1]);
        uv.y = packbf(acc[4*g+2], acc[4*g+3]);
        *(uint2*)(Pvj + (size_t)node*HC3 + h*C3 + P0) = uv;
      }
    }
  }
}

// ---------------- fused edge kernel: 32 edges x 1 head, 4 waves, 32x32 MFMA ----------------
__global__ __launch_bounds__(256, 3)
void k_edge_mfma(const unsigned short* __restrict__ ef_bf,   // sorted order
                 const unsigned short* __restrict__ q_bf, const unsigned short* __restrict__ k_bf,
                 const unsigned short* __restrict__ Pvi, const unsigned short* __restrict__ Pvj,
                 const int* __restrict__ ssrc, const int* __restrict__ sdst,
                 const unsigned short* __restrict__ WeA,
                 const unsigned short* __restrict__ WfA,
                 const unsigned short* __restrict__ WgA,
                 const float* __restrict__ lnAg, const float* __restrict__ lnAb,
                 const float* __restrict__ lnMg, const float* __restrict__ lnMb,
                 const float* __restrict__ bmsg,
                 float* __restrict__ agg)
{
  __shared__ __align__(16) union {
    unsigned short m[TE2][392];   // 25.1 KB (GEMM3 K-operand)
    float mf[TE2][132];           // 16.9 KB (post-LN msg)
  } u_s;
  __shared__ float red1[4][TE2][2];
  __shared__ float red2[4][TE2][2];
  __shared__ int sdst_s[TE2];

  const int t = threadIdx.x;
  const int w = t >> 6, lane = t & 63;
  const int col = lane & 31, hi = lane >> 5;
  const int e0 = blockIdx.x * TE2;
  const int h  = blockIdx.y;
  const int edge = e0 + col;
  const int dst = sdst[edge], src = ssrc[edge];
  if (t < TE2) sdst_s[t] = sdst[e0 + t];

  // ---- ef B-fragments: 8 K-chunks of 16 ----
  const unsigned short* efrow = ef_bf + (size_t)edge*CC + hi*8;
  bf16x8 bfr[8];
  #pragma unroll
  for (int kc = 0; kc < 8; ++kc) bfr[kc] = ldbf8(efrow + kc*16);

  // ---- q/k gathers (4 row-groups of 4 channels each) ----
  ushort4 q4[4], kd4[4], kj4[4];
  #pragma unroll
  for (int g = 0; g < 4; ++g){
    int c0 = w*32 + 8*g + 4*hi;
    q4[g]  = *(const ushort4*)(q_bf + (size_t)dst*HD + h*CC + c0);
    kd4[g] = *(const ushort4*)(k_bf + (size_t)dst*HD + h*CC + c0);
    kj4[g] = *(const ushort4*)(k_bf + (size_t)src*HD + h*CC + c0);
  }

  // ---- GEMM1: e^T rows [32w..32w+31] ----
  const unsigned short* WeAh = WeA + (size_t)h*CC*CC;
  f32x16 acc1;
  #pragma unroll
  for (int i = 0; i < 16; ++i) acc1[i] = 0.f;
  {
    const unsigned short* arow = WeAh + (size_t)(w*32 + col)*CC + hi*8;
    __builtin_amdgcn_s_setprio(1);
    #pragma unroll
    for (int kc = 0; kc < 8; ++kc)
      acc1 = __builtin_amdgcn_mfma_f32_32x32x16_bf16(ldbf8(arow + kc*16), bfr[kc], acc1, 0,0,0);
    __builtin_amdgcn_s_setprio(0);
  }

  // ---- alpha (unscaled) + LN sums; av[part*16+reg] ----
  float av[48];
  float s1 = 0.f, s2 = 0.f;
  #pragma unroll
  for (int reg = 0; reg < 16; ++reg){
    int g = reg >> 2, i = reg & 3;
    float qv  = bf2f(((const unsigned short*)&q4[g])[i]);
    float kdv = bf2f(((const unsigned short*)&kd4[g])[i]);
    float kjv = bf2f(((const unsigned short*)&kj4[g])[i]);
    float x0 = qv*kdv;
    float x1 = qv*kjv;
    float x2 = qv*acc1[reg];
    av[reg] = x0; av[16+reg] = x1; av[32+reg] = x2;
    s1 += x0+x1+x2;
    s2 += x0*x0+x1*x1+x2*x2;
  }
  s1 += __shfl_xor(s1, 32); s2 += __shfl_xor(s2, 32);
  if (hi == 0){ red1[w][col][0] = s1; red1[w][col][1] = s2; }
  __syncthreads();

  // ---- issue slow Pvi/Pvj gathers now (drain at barrier 2) ----
  ushort4 pi4[12], pj4[12];
  #pragma unroll
  for (int part = 0; part < 3; ++part){
    #pragma unroll
    for (int g = 0; g < 4; ++g){
      int P0 = w*96 + part*32 + 8*g + 4*hi;
      pi4[part*4+g] = *(const ushort4*)(Pvi + (size_t)dst*HC3 + h*C3 + P0);
      pj4[part*4+g] = *(const ushort4*)(Pvj + (size_t)src*HC3 + h*C3 + P0);
    }
  }

  // ---- gate = sigmoid(LN(alpha*SCALE)), in place over av ----
  {
    float S1 = red1[0][col][0] + red1[1][col][0] + red1[2][col][0] + red1[3][col][0];
    float S2 = red1[0][col][1] + red1[1][col][1] + red1[2][col][1] + red1[3][col][1];
    float mu = S1 * (1.0f/384.0f);
    float var = S2 * (1.0f/384.0f) - mu*mu;
    float coef = SCALE * rsqrtf(SCALE*SCALE*var + 1e-5f);
    #pragma unroll
    for (int part = 0; part < 3; ++part){
      #pragma unroll
      for (int g = 0; g < 4; ++g){
        int j0 = part*128 + w*32 + 8*g + 4*hi;
        float4 gg = *(const float4*)(lnAg + j0);
        float4 bb = *(const float4*)(lnAb + j0);
        av[part*16+4*g+0] = sigf((av[part*16+4*g+0]-mu)*coef*gg.x + bb.x);
        av[part*16+4*g+1] = sigf((av[part*16+4*g+1]-mu)*coef*gg.y + bb.y);
        av[part*16+4*g+2] = sigf((av[part*16+4*g+2]-mu)*coef*gg.z + bb.z);
        av[part*16+4*g+3] = sigf((av[part*16+4*g+3]-mu)*coef*gg.w + bb.w);
      }
    }
  }

  // ---- GEMM2: 3 tiles (parts), permuted rows P = 96w + 32*part + r ----
  const unsigned short* WfAh = WfA + (size_t)h*C3*CC;
  #pragma unroll
  for (int part = 0; part < 3; ++part){
    f32x16 acc2;
    #pragma unroll
    for (int i = 0; i < 16; ++i) acc2[i] = 0.f;
    const unsigned short* arow = WfAh + (size_t)(w*96 + part*32 + col)*CC + hi*8;
    __builtin_amdgcn_s_setprio(1);
    #pragma unroll
    for (int kc = 0; kc < 8; ++kc)
      acc2 = __builtin_amdgcn_mfma_f32_32x32x16_bf16(ldbf8(arow + kc*16), bfr[kc], acc2, 0,0,0);
    __builtin_amdgcn_s_setprio(0);
    #pragma unroll
    for (int g = 0; g < 4; ++g){
      float m0 = (acc2[4*g+0] + bf2f(pi4[part*4+g].x) + bf2f(pj4[part*4+g].x)) * av[part*16+4*g+0];
      float m1 = (acc2[4*g+1] + bf2f(pi4[part*4+g].y) + bf2f(pj4[part*4+g].y)) * av[part*16+4*g+1];
      float m2 = (acc2[4*g+2] + bf2f(pi4[part*4+g].z) + bf2f(pj4[part*4+g].z)) * av[part*16+4*g+2];
      float m3 = (acc2[4*g+3] + bf2f(pi4[part*4+g].w) + bf2f(pj4[part*4+g].w)) * av[part*16+4*g+3];
      uint2 uv;
      uv.x = packbf(m0, m1);
      uv.y = packbf(m2, m3);
      *(uint2*)&u_s.m[col][w*96 + part*32 + 8*g + 4*hi] = uv;
    }
  }
  __syncthreads();

  // ---- GEMM3: msg rows [32w..32w+31], K=384 (permuted, from LDS) ----
  f32x16 acc3;
  #pragma unroll
  for (int i = 0; i < 16; ++i) acc3[i] = 0.f;
  {
    const unsigned short* arow = WgA + (size_t)(w*32 + col)*C3 + hi*8;
    __builtin_amdgcn_s_setprio(1);
    #pragma unroll
    for (int kc = 0; kc < 24; ++kc)
      acc3 = __builtin_amdgcn_mfma_f32_32x32x16_bf16(ldbf8(arow + kc*16),
                                                     ldbf8(&u_s.m[col][kc*16 + hi*8]), acc3, 0,0,0);
    __builtin_amdgcn_s_setprio(0);
  }
  // ---- + bmsg, LN-128 sums ----
  float vals[16];
  {
    float t1 = 0.f, t2 = 0.f;
    #pragma unroll
    for (int g = 0; g < 4; ++g){
      float4 bq = *(const float4*)(bmsg + w*32 + 8*g + 4*hi);
      float v0 = acc3[4*g+0] + bq.x; float v1 = acc3[4*g+1] + bq.y;
      float v2 = acc3[4*g+2] + bq.z; float v3 = acc3[4*g+3] + bq.w;
      vals[4*g+0]=v0; vals[4*g+1]=v1; vals[4*g+2]=v2; vals[4*g+3]=v3;
      t1 += v0+v1+v2+v3; t2 += v0*v0+v1*v1+v2*v2+v3*v3;
    }
    t1 += __shfl_xor(t1, 32); t2 += __shfl_xor(t2, 32);
    if (hi == 0){ red2[w][col][0] = t1; red2[w][col][1] = t2; }
  }
  __syncthreads();   // red2 ready AND all GEMM3 reads of u_s.m complete
  {
    float S1 = red2[0][col][0] + red2[1][col][0] + red2[2][col][0] + red2[3][col][0];
    float S2 = red2[0][col][1] + red2[1][col][1] + red2[2][col][1] + red2[3][col][1];
    float mu = S1 * (1.0f/128.0f);
    float inv = rsqrtf(S2 * (1.0f/128.0f) - mu*mu + 1e-5f);
    #pragma unroll
    for (int g = 0; g < 4; ++g){
      int c0 = w*32 + 8*g + 4*hi;
      float4 gg = *(const float4*)(lnMg + c0);
      float4 bb = *(const float4*)(lnMb + c0);
      float4 r;
      r.x = (vals[4*g+0] - mu)*inv*gg.x + bb.x;
      r.y = (vals[4*g+1] - mu)*inv*gg.y + bb.y;
      r.z = (vals[4*g+2] - mu)*inv*gg.z + bb.z;
      r.w = (vals[4*g+3] - mu)*inv*gg.w + bb.w;
      *(float4*)&u_s.mf[col][c0] = r;
    }
  }
  __syncthreads();
  // ---- segmented reduce over sorted dst: 256 threads = 2 groups x 16 edges ----
  {
    int c = t & 127, grp = t >> 7;
    int base = grp*16;
    float run = 0.f;
    int d0 = sdst_s[base];
    #pragma unroll 4
    for (int e2 = base; e2 < base + 16; ++e2){
      int d = sdst_s[e2];
      if (d != d0){
        atomicAdd(agg + (size_t)d0*HD + h*CC + c, run);
        run = 0.f; d0 = d;
      }
      run += u_s.mf[e2][c];
    }
    atomicAdd(agg + (size_t)d0*HD + h*CC + c, run);
  }
}

// ---------------- o = agg @ Wc + bc via MFMA (split-bf16 agg) ; partial BN stats ----------------
__global__ __launch_bounds__(256)
void k_oc(const float* __restrict__ agg, const unsigned short* __restrict__ WcA,
          const float* __restrict__ bc, float* __restrict__ o, float* __restrict__ bns){
  const int t = threadIdx.x;
  const int wv = t >> 6, l = t & 63;
  const int lr = l & 15, lg = l >> 4;
  const int node = blockIdx.x*TE + lr;

  const float* arow_ = agg + (size_t)node*HD + lg*8;
  f32x4 acc[2]; acc[0] = f32x4{0.f,0.f,0.f,0.f}; acc[1] = f32x4{0.f,0.f,0.f,0.f};
  for (int ks = 0; ks < 16; ++ks){
    float fbuf[8];
    *(float4*)&fbuf[0] = *(const float4*)(arow_ + ks*32);
    *(float4*)&fbuf[4] = *(const float4*)(arow_ + ks*32 + 4);
    us8 hv, lv;
    #pragma unroll
    for (int i = 0; i < 8; ++i){
      float f = fbuf[i];
      unsigned int u = __builtin_bit_cast(unsigned int, f);
      hv[i] = (unsigned short)(u >> 16);                       // truncated hi
      float hf = __builtin_bit_cast(float, u & 0xFFFF0000u);
      lv[i] = f2bf(f - hf);                                    // residual lo
    }
    bf16x8 bhi = __builtin_bit_cast(bf16x8, hv);
    bf16x8 blo = __builtin_bit_cast(bf16x8, lv);
    __builtin_amdgcn_s_setprio(1);
    #pragma unroll
    for (int mt = 0; mt < 2; ++mt){
      bf16x8 a = ldbf8(WcA + (size_t)(wv*32 + mt*16 + lr)*HD + ks*32 + lg*8);
      acc[mt] = __builtin_amdgcn_mfma_f32_16x16x32_bf16(a, bhi, acc[mt], 0,0,0);
      acc[mt] = __builtin_amdgcn_mfma_f32_16x16x32_bf16(a, blo, acc[mt], 0,0,0);
    }
    __builtin_amdgcn_s_setprio(0);
  }
  #pragma unroll
  for (int mt = 0; mt < 2; ++mt){
    int c0 = wv*32 + mt*16 + lg*4;
    float4 bb = *(const float4*)(bc + c0);
    float4 ov;
    ov.x = acc[mt][0]+bb.x; ov.y = acc[mt][1]+bb.y; ov.z = acc[mt][2]+bb.z; ov.w = acc[mt][3]+bb.w;
    *(float4*)(o + (size_t)node*CC + c0) = ov;
    float vv[4] = {ov.x, ov.y, ov.z, ov.w};
    #pragma unroll
    for (int r = 0; r < 4; ++r){
      float a = vv[r], b = vv[r]*vv[r];
      a += __shfl_xor(a, 1); b += __shfl_xor(b, 1);
      a += __shfl_xor(a, 2); b += __shfl_xor(b, 2);
      a += __shfl_xor(a, 4); b += __shfl_xor(b, 4);
      a += __shfl_xor(a, 8); b += __shfl_xor(b, 8);
      if (lr == 0){ atomicAdd(&bns[c0+r], a); atomicAdd(&bns[CC+c0+r], b); }
    }
  }
}

// ---------------- BN(inline stats) + SiLU ----------------
__global__ void k_bnsilu(const float* __restrict__ o, const float* __restrict__ bns,
                         const float* __restrict__ g, const float* __restrict__ b,
                         float* __restrict__ h, unsigned short* __restrict__ h_bf){
  int i = blockIdx.x*256 + threadIdx.x;
  if (i < NN*CC){
    int c = i & 127;
    float mu = bns[c] * (1.0f/NN);
    float inv = rsqrtf(bns[CC+c] * (1.0f/NN) - mu*mu + 1e-5f);
    float z = (o[i] - mu) * inv * g[c] + b[c];
    float hv = siluf(z);
    h[i] = hv;
    h_bf[i] = f2bf(hv);
  }
}

__global__ void k_pool(const float* __restrict__ h, const int* __restrict__ batch,
                       float* __restrict__ pooled, float* __restrict__ counts){
  int i = blockIdx.x*256 + threadIdx.x;
  if (i < NN*CC){
    int n = i >> 7, c = i & 127;
    int g = batch[n];
    atomicAdd(&pooled[g*CC + c], h[i]);
    if (c == 0) atomicAdd(&counts[g], 1.0f);
  }
}

__global__ __launch_bounds__(128)
void k_final(const float* __restrict__ pooled, const float* __restrict__ counts,
             const float* __restrict__ Wfc, const float* __restrict__ bfc,
             float* __restrict__ out){
  __shared__ float psh[CC];
  int g = blockIdx.x; int t = threadIdx.x;
  float rc = 1.0f / fmaxf(counts[g], 1.0f);
  psh[t] = pooled[g*CC + t] * rc;
  __syncthreads();
  float acc = 0.f;
  for (int c = 0; c < CC; ++c) acc += psh[c] * Wfc[c*CC + t];
  out[g*CC + t] = siluf(acc + bfc[t]);
}

extern "C" void kernel_launch(void* const* d_in, const int* in_sizes, int n_in,
                              void* d_out, int out_size, void* d_ws, size_t ws_size,
                              hipStream_t stream){
  const float* x      = (const float*)d_in[0];
  const float* ea     = (const float*)d_in[1];
  const int*   ei     = (const int*)d_in[2];
  const int*   batch  = (const int*)d_in[3];
  const float* W_atom = (const float*)d_in[4];  const float* b_atom = (const float*)d_in[5];
  const float* W_rbf1 = (const float*)d_in[6];  const float* b_rbf1 = (const float*)d_in[7];
  const float* W_rbf2 = (const float*)d_in[8];  const float* b_rbf2 = (const float*)d_in[9];
  const float* Wq     = (const float*)d_in[10]; const float* bq     = (const float*)d_in[11];
  const float* Wk     = (const float*)d_in[12]; const float* bk     = (const float*)d_in[13];
  const float* Wv     = (const float*)d_in[14]; const float* bv     = (const float*)d_in[15];
  const float* We     = (const float*)d_in[16];
  const float* Wc     = (const float*)d_in[17]; const float* bc     = (const float*)d_in[18];
  const float* Wm     = (const float*)d_in[19]; const float* bm     = (const float*)d_in[20];
  const float* Wmsg   = (const float*)d_in[21]; const float* bmsg   = (const float*)d_in[22];
  const float* lnAg   = (const float*)d_in[23]; const float* lnAb   = (const float*)d_in[24];
  const float* lnMg   = (const float*)d_in[25]; const float* lnMb   = (const float*)d_in[26];
  const float* bng    = (const float*)d_in[27]; const float* bnb    = (const float*)d_in[28];
  const float* Wfc    = (const float*)d_in[29]; const float* bfc    = (const float*)d_in[30];

  float* ws = (float*)d_ws;
  size_t off = 0;
  auto alloc = [&](size_t n){ float* p = ws + off; off += n; return p; };
  float* h      = alloc((size_t)NN*CC);
  float* o      = alloc((size_t)NN*CC);
  float* agg    = alloc((size_t)NN*HD);
  float* bns    = alloc(2*CC);             // adjacent to agg: single memset covers both
  unsigned short* h_bf  = (unsigned short*)alloc((size_t)NN*CC/2);
  unsigned short* qb_bf = (unsigned short*)alloc((size_t)NN*HD/2);
  unsigned short* kb_bf = (unsigned short*)alloc((size_t)NN*HD/2);
  unsigned short* vb_bf = (unsigned short*)alloc((size_t)NN*HD/2);
  unsigned short* Pvi   = (unsigned short*)alloc((size_t)NN*HC3/2);
  unsigned short* Pvj   = (unsigned short*)alloc((size_t)NN*HC3/2);
  unsigned short* efs_bf= (unsigned short*)alloc((size_t)NE*CC/2);
  unsigned short* WeA   = (unsigned short*)alloc((size_t)NL*NH*CC*CC/2);
  unsigned short* WfA   = (unsigned short*)alloc((size_t)NL*NH*C3*CC/2);
  unsigned short* WvA   = (unsigned short*)alloc((size_t)NL*768*CC/2);
  unsigned short* WgA   = (unsigned short*)alloc((size_t)NL*CC*C3/2);
  unsigned short* WqkvA = (unsigned short*)alloc((size_t)NL*1536*CC/2);
  unsigned short* WcA   = (unsigned short*)alloc((size_t)NL*CC*HD/2);
  int* cnt    = (int*)alloc(8192);
  int* offs   = (int*)alloc(NN);
  int* cursor = (int*)alloc(NN);
  int* sperm  = (int*)alloc(NE);
  int* iperm  = (int*)alloc(NE);
  int* ssrc   = (int*)alloc(NE);
  int* sdst   = (int*)alloc(NE);
  float* pooled = alloc((size_t)NG*CC);
  float* counts = alloc(NG);

  if (off * sizeof(float) > ws_size){
    hipMemsetAsync(d_out, 0x7F, (size_t)out_size*sizeof(float), stream);
    return;
  }

  const int* srcI = ei;
  const int* dstI = ei + NE;

  // ---- sort edges by dst (once; reused by all 5 layers) ----
  hipMemsetAsync(cnt, 0, 8192*sizeof(int), stream);
  k_hist<<<(NE+255)/256, 256, 0, stream>>>(dstI, cnt);
  k_scan<<<1, 1024, 0, stream>>>(cnt, offs, cursor);
  k_scatter<<<(NE+255)/256, 256, 0, stream>>>(dstI, cursor, sperm, iperm);
  k_meta<<<(NE+255)/256, 256, 0, stream>>>(sperm, srcI, dstI, ssrc, sdst);

  // ---- weight prep ----
  k_prep_we<<<(NL*NH*CC*CC + 255)/256, 256, 0, stream>>>(We, WeA);
  k_prep_wv<<<(NL*768*CC + 255)/256, 256, 0, stream>>>(Wm, WvA);
  k_prep_wg<<<(NL*CC*C3 + 255)/256, 256, 0, stream>>>(Wmsg, WgA);
  k_prep_wf<<<NL*NH*C3, 128, 0, stream>>>(We, Wm, WfA);
  k_prep_wqkv<<<(NL*1536*CC + 255)/256, 256, 0, stream>>>(Wq, Wk, Wv, WqkvA);
  k_prep_wc<<<(NL*CC*HD + 255)/256, 256, 0, stream>>>(Wc, WcA);

  k_stem<<<NN/8, 128, 0, stream>>>(x, W_atom, b_atom, h, h_bf);
  k_rbf<<<NE/8, 128, 0, stream>>>(ea, W_rbf1, b_rbf1, W_rbf2, b_rbf2, iperm, efs_bf);

  for (int l = 0; l < NL; ++l){
    const float* bq_l   = bq   + (size_t)l*HD;
    const float* bk_l   = bk   + (size_t)l*HD;
    const float* bv_l   = bv   + (size_t)l*HD;
    const float* bc_l   = bc   + (size_t)l*CC;
    const float* bm_l   = bm   + (size_t)l*C3;
    const float* bmsg_l = bmsg + (size_t)l*CC;
    const float* lnAg_l = lnAg + (size_t)l*C3;      const float* lnAb_l = lnAb + (size_t)l*C3;
    const float* lnMg_l = lnMg + (size_t)l*CC;      const float* lnMb_l = lnMb + (size_t)l*CC;
    const float* bng_l  = bng  + (size_t)l*CC;      const float* bnb_l  = bnb  + (size_t)l*CC;
    const unsigned short* WeA_l = WeA + (size_t)l*NH*CC*CC;
    const unsigned short* WfA_l = WfA + (size_t)l*NH*C3*CC;
    const unsigned short* WvA_l = WvA + (size_t)l*768*CC;
    const unsigned short* WgA_l = WgA + (size_t)l*CC*C3;
    const unsigned short* WqkvA_l = WqkvA + (size_t)l*1536*CC;
    const unsigned short* WcA_l = WcA + (size_t)l*CC*HD;

    k_qkv_mfma<<<dim3(NN/32, 3), 256, 0, stream>>>(h_bf, WqkvA_l, bq_l, bk_l, bv_l,
                                                   qb_bf, kb_bf, vb_bf);
    k_pv_mfma<<<dim3(NN/32, NH), 256, 0, stream>>>(vb_bf, WvA_l, bm_l, Pvi, Pvj);

    hipMemsetAsync(agg, 0, ((size_t)NN*HD + 2*CC)*sizeof(float), stream);  // agg + bns

    k_edge_mfma<<<dim3(NEB, NH), 256, 0, stream>>>(efs_bf, qb_bf, kb_bf, Pvi, Pvj, ssrc, sdst,
                                                   WeA_l, WfA_l, WgA_l,
                                                   lnAg_l, lnAb_l, lnMg_l, lnMb_l, bmsg_l, agg);

    k_oc<<<NN/TE, 256, 0, stream>>>(agg, WcA_l, bc_l, o, bns);
    k_bnsilu<<<(NN*CC+255)/256, 256, 0, stream>>>(o, bns, bng_l, bnb_l, h, h_bf);
  }

  hipMemsetAsync(pooled, 0, ((size_t)NG*CC + NG)*sizeof(float), stream);
  k_pool<<<(NN*CC+255)/256, 256, 0, stream>>>(h, batch, pooled, counts);
  k_final<<<NG, 128, 0, stream>>>(pooled, counts, Wfc, bfc, (float*)d_out);
}

// Round 17
// 3649.190 us; speedup vs baseline: 1.0428x; 1.0428x over previous
//
#include <hip/hip_runtime.h>
#include <math.h>

#define NN 8000
#define NE 100000
#define NG 256
#define CC 128
#define NH 4
#define HD 512
#define C3 384
#define HC3 1536
#define NL 5
#define AF 92
#define TE 16
#define TE2 32
#define NEB (NE/TE2)
#define SCALE 0.05103103630798288f

typedef __attribute__((ext_vector_type(8))) __bf16 bf16x8;
typedef __attribute__((ext_vector_type(4))) float f32x4;
typedef __attribute__((ext_vector_type(16))) float f32x16;
typedef __attribute__((ext_vector_type(8))) unsigned short us8;

static __device__ __forceinline__ bf16x8 ldbf8(const unsigned short* p){
  us8 v = *reinterpret_cast<const us8*>(p);
  return __builtin_bit_cast(bf16x8, v);
}
static __device__ __forceinline__ unsigned short f2bf(float f){
  unsigned int u = __builtin_bit_cast(unsigned int, f);
  u += 0x7FFFu + ((u >> 16) & 1u);
  return (unsigned short)(u >> 16);
}
static __device__ __forceinline__ float bf2f(unsigned short u){
  unsigned int x = ((unsigned int)u) << 16;
  return __builtin_bit_cast(float, x);
}
static __device__ __forceinline__ unsigned int packbf(float a, float b){
  return (unsigned int)f2bf(a) | ((unsigned int)f2bf(b) << 16);
}
static __device__ __forceinline__ float sigf(float x){ return 1.0f/(1.0f+__expf(-x)); }
static __device__ __forceinline__ float siluf(float x){ return x/(1.0f+__expf(-x)); }
static __device__ __forceinline__ float softplusf(float x){
  return x > 0.0f ? x + __logf(1.0f+__expf(-x)) : __logf(1.0f+__expf(x));
}
// channel permutation: P (permuted pos in [0,384)) -> original channel j
// tile t=P/32 (0..11), wave w=t/3, part=t%3, row r=P%32 -> j = part*128 + w*32 + r
static __device__ __forceinline__ int permJ(int P){
  int tt = P >> 5;
  int r  = P & 31;
  int w  = tt / 3, part = tt - 3*w;
  return part*128 + w*32 + r;
}

// ================= edge sort by dst (once per call) =================
__global__ void k_hist(const int* __restrict__ dstI, int* __restrict__ cnt){
  int i = blockIdx.x*256 + threadIdx.x;
  if (i < NE) atomicAdd(&cnt[dstI[i]], 1);
}
__global__ __launch_bounds__(1024)
void k_scan(const int* __restrict__ cnt, int* __restrict__ offs, int* __restrict__ cursor){
  __shared__ int a_s[1024], b_s[1024];
  int t = threadIdx.x;
  int base = t*8;
  int v[8]; int s = 0;
  #pragma unroll
  for (int j = 0; j < 8; ++j){
    int c = (base+j < NN) ? cnt[base+j] : 0;
    v[j] = s; s += c;
  }
  a_s[t] = s; __syncthreads();
  int* srcp = a_s; int* dstp = b_s;
  for (int off = 1; off < 1024; off <<= 1){
    int x = srcp[t];
    if (t >= off) x += srcp[t-off];
    dstp[t] = x; __syncthreads();
    int* tmp = srcp; srcp = dstp; dstp = tmp;
  }
  int excl = (t == 0) ? 0 : srcp[t-1];
  #pragma unroll
  for (int j = 0; j < 8; ++j){
    if (base+j < NN){ offs[base+j] = excl + v[j]; cursor[base+j] = excl + v[j]; }
  }
}
__global__ void k_scatter(const int* __restrict__ dstI, int* __restrict__ cursor,
                          int* __restrict__ sperm, int* __restrict__ iperm){
  int i = blockIdx.x*256 + threadIdx.x;
  if (i < NE){
    int d = dstI[i];
    int pos = atomicAdd(&cursor[d], 1);
    sperm[pos] = i;
    iperm[i] = pos;
  }
}
__global__ void k_meta(const int* __restrict__ sperm, const int* __restrict__ srcI,
                       const int* __restrict__ dstI, int* __restrict__ ssrc,
                       int* __restrict__ sdst){
  int i = blockIdx.x*256 + threadIdx.x;
  if (i < NE){ int e = sperm[i]; ssrc[i] = srcI[e]; sdst[i] = dstI[e]; }
}

// ================= weight prep =================
__global__ void k_prep_we(const float* __restrict__ We, unsigned short* __restrict__ WeA){
  size_t i = (size_t)blockIdx.x*256 + threadIdx.x;
  if (i >= (size_t)NL*NH*CC*CC) return;
  int k = i & 127; int r = (i>>7)&127; int hh = (i>>14)&3; int li = (int)(i>>16);
  WeA[i] = f2bf(We[((size_t)li*CC + k)*HD + hh*CC + r]);
}
// WvA rows (768): R<384 -> Pvi row P=R: Wm[k][permJ(P)] ; R>=384 -> Pvj row: Wm[128+k][permJ(P)]
__global__ void k_prep_wv(const float* __restrict__ Wm, unsigned short* __restrict__ WvA){
  size_t i = (size_t)blockIdx.x*256 + threadIdx.x;
  if (i >= (size_t)NL*768*CC) return;
  int k = i & 127; int R = (int)((i>>7) % 768); int li = (int)(i / (768*CC));
  int P = (R < C3) ? R : R - C3;
  int j = permJ(P);
  float val = (R < C3) ? Wm[((size_t)li*C3 + k)*C3 + j]
                       : Wm[((size_t)li*C3 + 128 + k)*C3 + j];
  WvA[i] = f2bf(val);
}
__global__ void k_prep_wg(const float* __restrict__ Wmsg, unsigned short* __restrict__ WgA){
  size_t i = (size_t)blockIdx.x*256 + threadIdx.x;
  if (i >= (size_t)NL*CC*C3) return;
  int P = (int)(i % C3); int c = (int)((i / C3) % CC); int li = (int)(i / ((size_t)CC*C3));
  WgA[i] = f2bf(Wmsg[((size_t)li*C3 + permJ(P))*CC + c]);
}
__global__ __launch_bounds__(128)
void k_prep_wf(const float* __restrict__ We, const float* __restrict__ Wm,
               unsigned short* __restrict__ WfA){
  int b = blockIdx.x;                 // b = ((li*4+hh)*384 + P)
  int P = b % C3; int hh = (b / C3) & 3; int li = b / (C3*NH);
  int o = permJ(P);
  __shared__ float wcol[CC];
  int t = threadIdx.x;
  wcol[t] = Wm[((size_t)li*C3 + 256 + t)*C3 + o];
  __syncthreads();
  const float* werow = We + ((size_t)li*CC + t)*HD + hh*CC;
  float acc = 0.f;
  #pragma unroll 4
  for (int c = 0; c < CC; ++c) acc += werow[c] * wcol[c];
  WfA[(((size_t)li*NH + hh)*C3 + P)*CC + t] = f2bf(acc);
}
// WqkvA[l][m][k]: m<512 -> Wq[l][k][m]; 512..1023 -> Wk; else Wv  (bf16 A-operand)
__global__ void k_prep_wqkv(const float* __restrict__ Wq, const float* __restrict__ Wk,
                            const float* __restrict__ Wv, unsigned short* __restrict__ WA){
  size_t i = (size_t)blockIdx.x*256 + threadIdx.x;
  if (i >= (size_t)NL*1536*CC) return;
  int k = i & 127; int m = (int)((i>>7) % 1536); int li = (int)(i / ((size_t)1536*CC));
  const float* W = (m < 512) ? Wq : (m < 1024) ? Wk : Wv;
  int mm = m & 511;
  WA[i] = f2bf(W[((size_t)li*CC + k)*HD + mm]);
}
// WcA[l][r][k] = Wc[l][k][r]  (bf16 A-operand for k_oc; all layers, once)
__global__ void k_prep_wc(const float* __restrict__ Wc, unsigned short* __restrict__ WcA){
  size_t i = (size_t)blockIdx.x*256 + threadIdx.x;
  if (i >= (size_t)NL*CC*HD) return;
  int k = (int)(i & 511); int r = (int)((i>>9) & 127); int li = (int)(i >> 16);
  WcA[i] = f2bf(Wc[((size_t)li*HD + k)*CC + r]);
}

// ---------------- stem (writes f32 h + bf16 h) ----------------
__global__ __launch_bounds__(128)
void k_stem(const float* __restrict__ x, const float* __restrict__ W,
            const float* __restrict__ b, float* __restrict__ h,
            unsigned short* __restrict__ h_bf){
  __shared__ float xs[8][AF];
  int n0 = blockIdx.x*8;
  int t = threadIdx.x;
  for (int i = t; i < 8*AF; i += 128){ xs[i/AF][i%AF] = x[(size_t)n0*AF + i]; }
  __syncthreads();
  float acc[8] = {};
  for (int f = 0; f < AF; ++f){
    float w = W[f*CC + t];
    #pragma unroll
    for (int n = 0; n < 8; ++n) acc[n] += xs[n][f]*w;
  }
  float bb = b[t];
  #pragma unroll
  for (int n = 0; n < 8; ++n){
    float hv = acc[n] + bb;
    h[(size_t)(n0+n)*CC + t] = hv;
    h_bf[(size_t)(n0+n)*CC + t] = f2bf(hv);
  }
}

// ---------------- rbf MLP -> efs_bf (written directly in SORTED order) ----------------
__global__ __launch_bounds__(128)
void k_rbf(const float* __restrict__ ea, const float* __restrict__ W1, const float* __restrict__ b1,
           const float* __restrict__ W2, const float* __restrict__ b2,
           const int* __restrict__ iperm, unsigned short* __restrict__ efs){
  __shared__ __align__(16) float rs[8][CC];
  __shared__ __align__(16) float ss[8][CC];
  __shared__ float dv[8];
  __shared__ int ip_s[8];
  int e0 = blockIdx.x*8; int t = threadIdx.x;
  if (t < 8){ dv[t] = ea[e0 + t]; ip_s[t] = iperm[e0 + t]; }
  __syncthreads();
  float center = (8.0f/127.0f) * (float)t;
  const float gamma = 15.875f;
  #pragma unroll
  for (int n = 0; n < 8; ++n){ float d = dv[n] - center; rs[n][t] = __expf(-gamma*d*d); }
  __syncthreads();
  {
    float acc[8] = {};
    for (int c0 = 0; c0 < CC; c0 += 4){
      float w0 = W1[(c0+0)*CC+t], w1 = W1[(c0+1)*CC+t], w2 = W1[(c0+2)*CC+t], w3 = W1[(c0+3)*CC+t];
      #pragma unroll
      for (int n = 0; n < 8; ++n){
        float4 r4 = *(const float4*)&rs[n][c0];
        acc[n] += r4.x*w0 + r4.y*w1 + r4.z*w2 + r4.w*w3;
      }
    }
    float bb = b1[t];
    #pragma unroll
    for (int n = 0; n < 8; ++n) ss[n][t] = softplusf(acc[n] + bb);
  }
  __syncthreads();
  {
    float acc[8] = {};
    for (int c0 = 0; c0 < CC; c0 += 4){
      float w0 = W2[(c0+0)*CC+t], w1 = W2[(c0+1)*CC+t], w2 = W2[(c0+2)*CC+t], w3 = W2[(c0+3)*CC+t];
      #pragma unroll
      for (int n = 0; n < 8; ++n){
        float4 r4 = *(const float4*)&ss[n][c0];
        acc[n] += r4.x*w0 + r4.y*w1 + r4.z*w2 + r4.w*w3;
      }
    }
    float bb = b2[t];
    #pragma unroll
    for (int n = 0; n < 8; ++n) efs[(size_t)ip_s[n]*CC + t] = f2bf(acc[n] + bb);
  }
}

// ---------------- q/k/v via 32x32 MFMA (grid: (NN/32, 3)) ----------------
__global__ __launch_bounds__(256)
void k_qkv_mfma(const unsigned short* __restrict__ h_bf,
                const unsigned short* __restrict__ WA,   // [1536][128] this layer
                const float* __restrict__ bq_, const float* __restrict__ bk_,
                const float* __restrict__ bv_,
                unsigned short* __restrict__ qo, unsigned short* __restrict__ ko,
                unsigned short* __restrict__ vo){
  const int t = threadIdx.x;
  const int w = t >> 6, lane = t & 63;
  const int col = lane & 31, hi = lane >> 5;
  const int node = blockIdx.x * 32 + col;
  const int yw = blockIdx.y;   // 0=q, 1=k, 2=v

  const unsigned short* hrow = h_bf + (size_t)node*CC + hi*8;
  bf16x8 bfr[8];
  #pragma unroll
  for (int kc = 0; kc < 8; ++kc) bfr[kc] = ldbf8(hrow + kc*16);

  const float* bias = (yw == 0) ? bq_ : (yw == 1) ? bk_ : bv_;
  unsigned short* outp = (yw == 0) ? qo : (yw == 1) ? ko : vo;
  const unsigned short* Wbase = WA + (size_t)yw*512*CC;

  #pragma unroll
  for (int mt = 0; mt < 4; ++mt){
    f32x16 acc;
    #pragma unroll
    for (int i = 0; i < 16; ++i) acc[i] = 0.f;
    const unsigned short* arow = Wbase + (size_t)(w*128 + mt*32 + col)*CC + hi*8;
    #pragma unroll
    for (int kc = 0; kc < 8; ++kc)
      acc = __builtin_amdgcn_mfma_f32_32x32x16_bf16(ldbf8(arow + kc*16), bfr[kc], acc, 0,0,0);
    #pragma unroll
    for (int g = 0; g < 4; ++g){
      int cb = w*128 + mt*32 + 8*g + 4*hi;
      float4 bb = *(const float4*)(bias + cb);
      uint2 uv;
      uv.x = packbf(acc[4*g+0]+bb.x, acc[4*g+1]+bb.y);
      uv.y = packbf(acc[4*g+2]+bb.z, acc[4*g+3]+bb.w);
      *(uint2*)(outp + (size_t)node*HD + cb) = uv;
    }
  }
}

// ---------------- Pvi/Pvj via 32x32 MFMA (grid: (NN/32, NH)) ----------------
__global__ __launch_bounds__(256)
void k_pv_mfma(const unsigned short* __restrict__ v_bf, const unsigned short* __restrict__ WvA,
               const float* __restrict__ bm,
               unsigned short* __restrict__ Pvi, unsigned short* __restrict__ Pvj){
  const int t = threadIdx.x;
  const int w = t >> 6, lane = t & 63;
  const int col = lane & 31, hi = lane >> 5;
  const int node = blockIdx.x * 32 + col;
  const int h = blockIdx.y;

  const unsigned short* vrow = v_bf + (size_t)node*HD + h*CC + hi*8;
  bf16x8 bfr[8];
  #pragma unroll
  for (int kc = 0; kc < 8; ++kc) bfr[kc] = ldbf8(vrow + kc*16);

  #pragma unroll
  for (int mt = 0; mt < 6; ++mt){
    f32x16 acc;
    #pragma unroll
    for (int i = 0; i < 16; ++i) acc[i] = 0.f;
    int R0 = w*192 + mt*32;                 // tile rows [R0, R0+32) — pure Pvi or pure Pvj
    const unsigned short* arow = WvA + (size_t)(R0 + col)*CC + hi*8;
    #pragma unroll
    for (int kc = 0; kc < 8; ++kc)
      acc = __builtin_amdgcn_mfma_f32_32x32x16_bf16(ldbf8(arow + kc*16), bfr[kc], acc, 0,0,0);
    if (R0 < C3){
      #pragma unroll
      for (int g = 0; g < 4; ++g){
        int P0 = R0 + 8*g + 4*hi;
        int j0 = permJ(P0);                 // 4 consecutive j's
        float4 bq = *(const float4*)(bm + j0);
        uint2 uv;
        uv.x = packbf(acc[4*g+0]+bq.x, acc[4*g+1]+bq.y);
        uv.y = packbf(acc[4*g+2]+bq.z, acc[4*g+3]+bq.w);
        *(uint2*)(Pvi + (size_t)node*HC3 + h*C3 + P0) = uv;
      }
    } else {
      #pragma unroll
      for (int g = 0; g < 4; ++g){
        int P0 = R0 - C3 + 8*g + 4*hi;
        uint2 uv;
        uv.x = packbf(acc[4*g+0], acc[4*g+1]);
        uv.y = packbf(acc[4*g+2], acc[4*g+3]);
        *(uint2*)(Pvj + (size_t)node*HC3 + h*C3 + P0) = uv;
      }
    }
  }
}

// ---------------- fused edge kernel: 32 edges x 1 head, 4 waves, 32x32 MFMA ----------------
__global__ __launch_bounds__(256, 3)
void k_edge_mfma(const unsigned short* __restrict__ ef_bf,   // sorted order
                 const unsigned short* __restrict__ q_bf, const unsigned short* __restrict__ k_bf,
                 const unsigned short* __restrict__ Pvi, const unsigned short* __restrict__ Pvj,
                 const int* __restrict__ ssrc, const int* __restrict__ sdst,
                 const unsigned short* __restrict__ WeA,
                 const unsigned short* __restrict__ WfA,
                 const unsigned short* __restrict__ WgA,
                 const float* __restrict__ lnAg, const float* __restrict__ lnAb,
                 const float* __restrict__ lnMg, const float* __restrict__ lnMb,
                 const float* __restrict__ bmsg,
                 float* __restrict__ agg)
{
  __shared__ __align__(16) union {
    unsigned short m[TE2][392];   // 25.1 KB (GEMM3 K-operand)
    float mf[TE2][132];           // 16.9 KB (post-LN msg)
  } u_s;
  __shared__ float red1[4][TE2][2];
  __shared__ float red2[4][TE2][2];
  __shared__ int sdst_s[TE2];

  const int t = threadIdx.x;
  const int w = t >> 6, lane = t & 63;
  const int col = lane & 31, hi = lane >> 5;
  const int e0 = blockIdx.x * TE2;
  const int h  = blockIdx.y;
  const int edge = e0 + col;
  const int dst = sdst[edge], src = ssrc[edge];
  if (t < TE2) sdst_s[t] = sdst[e0 + t];

  // ---- ef B-fragments: 8 K-chunks of 16 ----
  const unsigned short* efrow = ef_bf + (size_t)edge*CC + hi*8;
  bf16x8 bfr[8];
  #pragma unroll
  for (int kc = 0; kc < 8; ++kc) bfr[kc] = ldbf8(efrow + kc*16);

  // ---- q/k gathers (4 row-groups of 4 channels each) ----
  ushort4 q4[4], kd4[4], kj4[4];
  #pragma unroll
  for (int g = 0; g < 4; ++g){
    int c0 = w*32 + 8*g + 4*hi;
    q4[g]  = *(const ushort4*)(q_bf + (size_t)dst*HD + h*CC + c0);
    kd4[g] = *(const ushort4*)(k_bf + (size_t)dst*HD + h*CC + c0);
    kj4[g] = *(const ushort4*)(k_bf + (size_t)src*HD + h*CC + c0);
  }

  // ---- GEMM1: e^T rows [32w..32w+31] ----
  const unsigned short* WeAh = WeA + (size_t)h*CC*CC;
  f32x16 acc1;
  #pragma unroll
  for (int i = 0; i < 16; ++i) acc1[i] = 0.f;
  {
    const unsigned short* arow = WeAh + (size_t)(w*32 + col)*CC + hi*8;
    #pragma unroll
    for (int kc = 0; kc < 8; ++kc)
      acc1 = __builtin_amdgcn_mfma_f32_32x32x16_bf16(ldbf8(arow + kc*16), bfr[kc], acc1, 0,0,0);
  }

  // ---- alpha (unscaled) + LN sums; av[part*16+reg] ----
  float av[48];
  float s1 = 0.f, s2 = 0.f;
  #pragma unroll
  for (int reg = 0; reg < 16; ++reg){
    int g = reg >> 2, i = reg & 3;
    float qv  = bf2f(((const unsigned short*)&q4[g])[i]);
    float kdv = bf2f(((const unsigned short*)&kd4[g])[i]);
    float kjv = bf2f(((const unsigned short*)&kj4[g])[i]);
    float x0 = qv*kdv;
    float x1 = qv*kjv;
    float x2 = qv*acc1[reg];
    av[reg] = x0; av[16+reg] = x1; av[32+reg] = x2;
    s1 += x0+x1+x2;
    s2 += x0*x0+x1*x1+x2*x2;
  }
  s1 += __shfl_xor(s1, 32); s2 += __shfl_xor(s2, 32);
  if (hi == 0){ red1[w][col][0] = s1; red1[w][col][1] = s2; }
  __syncthreads();

  // ---- issue slow Pvi/Pvj gathers now (drain at barrier 2) ----
  ushort4 pi4[12], pj4[12];
  #pragma unroll
  for (int part = 0; part < 3; ++part){
    #pragma unroll
    for (int g = 0; g < 4; ++g){
      int P0 = w*96 + part*32 + 8*g + 4*hi;
      pi4[part*4+g] = *(const ushort4*)(Pvi + (size_t)dst*HC3 + h*C3 + P0);
      pj4[part*4+g] = *(const ushort4*)(Pvj + (size_t)src*HC3 + h*C3 + P0);
    }
  }

  // ---- gate = sigmoid(LN(alpha*SCALE)), in place over av ----
  {
    float S1 = red1[0][col][0] + red1[1][col][0] + red1[2][col][0] + red1[3][col][0];
    float S2 = red1[0][col][1] + red1[1][col][1] + red1[2][col][1] + red1[3][col][1];
    float mu = S1 * (1.0f/384.0f);
    float var = S2 * (1.0f/384.0f) - mu*mu;
    float coef = SCALE * rsqrtf(SCALE*SCALE*var + 1e-5f);
    #pragma unroll
    for (int part = 0; part < 3; ++part){
      #pragma unroll
      for (int g = 0; g < 4; ++g){
        int j0 = part*128 + w*32 + 8*g + 4*hi;
        float4 gg = *(const float4*)(lnAg + j0);
        float4 bb = *(const float4*)(lnAb + j0);
        av[part*16+4*g+0] = sigf((av[part*16+4*g+0]-mu)*coef*gg.x + bb.x);
        av[part*16+4*g+1] = sigf((av[part*16+4*g+1]-mu)*coef*gg.y + bb.y);
        av[part*16+4*g+2] = sigf((av[part*16+4*g+2]-mu)*coef*gg.z + bb.z);
        av[part*16+4*g+3] = sigf((av[part*16+4*g+3]-mu)*coef*gg.w + bb.w);
      }
    }
  }

  // ---- GEMM2: 3 tiles (parts), permuted rows P = 96w + 32*part + r ----
  const unsigned short* WfAh = WfA + (size_t)h*C3*CC;
  #pragma unroll
  for (int part = 0; part < 3; ++part){
    f32x16 acc2;
    #pragma unroll
    for (int i = 0; i < 16; ++i) acc2[i] = 0.f;
    const unsigned short* arow = WfAh + (size_t)(w*96 + part*32 + col)*CC + hi*8;
    #pragma unroll
    for (int kc = 0; kc < 8; ++kc)
      acc2 = __builtin_amdgcn_mfma_f32_32x32x16_bf16(ldbf8(arow + kc*16), bfr[kc], acc2, 0,0,0);
    #pragma unroll
    for (int g = 0; g < 4; ++g){
      float m0 = (acc2[4*g+0] + bf2f(pi4[part*4+g].x) + bf2f(pj4[part*4+g].x)) * av[part*16+4*g+0];
      float m1 = (acc2[4*g+1] + bf2f(pi4[part*4+g].y) + bf2f(pj4[part*4+g].y)) * av[part*16+4*g+1];
      float m2 = (acc2[4*g+2] + bf2f(pi4[part*4+g].z) + bf2f(pj4[part*4+g].z)) * av[part*16+4*g+2];
      float m3 = (acc2[4*g+3] + bf2f(pi4[part*4+g].w) + bf2f(pj4[part*4+g].w)) * av[part*16+4*g+3];
      uint2 uv;
      uv.x = packbf(m0, m1);
      uv.y = packbf(m2, m3);
      *(uint2*)&u_s.m[col][w*96 + part*32 + 8*g + 4*hi] = uv;
    }
  }
  __syncthreads();

  // ---- GEMM3: msg rows [32w..32w+31], K=384 (permuted, from LDS) ----
  f32x16 acc3;
  #pragma unroll
  for (int i = 0; i < 16; ++i) acc3[i] = 0.f;
  {
    const unsigned short* arow = WgA + (size_t)(w*32 + col)*C3 + hi*8;
    #pragma unroll
    for (int kc = 0; kc < 24; ++kc)
      acc3 = __builtin_amdgcn_mfma_f32_32x32x16_bf16(ldbf8(arow + kc*16),
                                                     ldbf8(&u_s.m[col][kc*16 + hi*8]), acc3, 0,0,0);
  }
  // ---- + bmsg, LN-128 sums ----
  float vals[16];
  {
    float t1 = 0.f, t2 = 0.f;
    #pragma unroll
    for (int g = 0; g < 4; ++g){
      float4 bq = *(const float4*)(bmsg + w*32 + 8*g + 4*hi);
      float v0 = acc3[4*g+0] + bq.x; float v1 = acc3[4*g+1] + bq.y;
      float v2 = acc3[4*g+2] + bq.z; float v3 = acc3[4*g+3] + bq.w;
      vals[4*g+0]=v0; vals[4*g+1]=v1; vals[4*g+2]=v2; vals[4*g+3]=v3;
      t1 += v0+v1+v2+v3; t2 += v0*v0+v1*v1+v2*v2+v3*v3;
    }
    t1 += __shfl_xor(t1, 32); t2 += __shfl_xor(t2, 32);
    if (hi == 0){ red2[w][col][0] = t1; red2[w][col][1] = t2; }
  }
  __syncthreads();   // red2 ready AND all GEMM3 reads of u_s.m complete
  {
    float S1 = red2[0][col][0] + red2[1][col][0] + red2[2][col][0] + red2[3][col][0];
    float S2 = red2[0][col][1] + red2[1][col][1] + red2[2][col][1] + red2[3][col][1];
    float mu = S1 * (1.0f/128.0f);
    float inv = rsqrtf(S2 * (1.0f/128.0f) - mu*mu + 1e-5f);
    #pragma unroll
    for (int g = 0; g < 4; ++g){
      int c0 = w*32 + 8*g + 4*hi;
      float4 gg = *(const float4*)(lnMg + c0);
      float4 bb = *(const float4*)(lnMb + c0);
      float4 r;
      r.x = (vals[4*g+0] - mu)*inv*gg.x + bb.x;
      r.y = (vals[4*g+1] - mu)*inv*gg.y + bb.y;
      r.z = (vals[4*g+2] - mu)*inv*gg.z + bb.z;
      r.w = (vals[4*g+3] - mu)*inv*gg.w + bb.w;
      *(float4*)&u_s.mf[col][c0] = r;
    }
  }
  __syncthreads();
  // ---- segmented reduce over sorted dst: 256 threads = 2 groups x 16 edges ----
  {
    int c = t & 127, grp = t >> 7;
    int base = grp*16;
    float run = 0.f;
    int d0 = sdst_s[base];
    #pragma unroll 4
    for (int e2 = base; e2 < base + 16; ++e2){
      int d = sdst_s[e2];
      if (d != d0){
        atomicAdd(agg + (size_t)d0*HD + h*CC + c, run);
        run = 0.f; d0 = d;
      }
      run += u_s.mf[e2][c];
    }
    atomicAdd(agg + (size_t)d0*HD + h*CC + c, run);
  }
}

// ---------------- o = agg @ Wc + bc via MFMA (split-bf16 agg) ; partial BN stats ----------------
__global__ __launch_bounds__(256)
void k_oc(const float* __restrict__ agg, const unsigned short* __restrict__ WcA,
          const float* __restrict__ bc, float* __restrict__ o, float* __restrict__ bns){
  const int t = threadIdx.x;
  const int wv = t >> 6, l = t & 63;
  const int lr = l & 15, lg = l >> 4;
  const int node = blockIdx.x*TE + lr;

  const float* arow_ = agg + (size_t)node*HD + lg*8;
  f32x4 acc[2]; acc[0] = f32x4{0.f,0.f,0.f,0.f}; acc[1] = f32x4{0.f,0.f,0.f,0.f};
  for (int ks = 0; ks < 16; ++ks){
    float fbuf[8];
    *(float4*)&fbuf[0] = *(const float4*)(arow_ + ks*32);
    *(float4*)&fbuf[4] = *(const float4*)(arow_ + ks*32 + 4);
    us8 hv, lv;
    #pragma unroll
    for (int i = 0; i < 8; ++i){
      float f = fbuf[i];
      unsigned int u = __builtin_bit_cast(unsigned int, f);
      hv[i] = (unsigned short)(u >> 16);                       // truncated hi
      float hf = __builtin_bit_cast(float, u & 0xFFFF0000u);
      lv[i] = f2bf(f - hf);                                    // residual lo
    }
    bf16x8 bhi = __builtin_bit_cast(bf16x8, hv);
    bf16x8 blo = __builtin_bit_cast(bf16x8, lv);
    #pragma unroll
    for (int mt = 0; mt < 2; ++mt){
      bf16x8 a = ldbf8(WcA + (size_t)(wv*32 + mt*16 + lr)*HD + ks*32 + lg*8);
      acc[mt] = __builtin_amdgcn_mfma_f32_16x16x32_bf16(a, bhi, acc[mt], 0,0,0);
      acc[mt] = __builtin_amdgcn_mfma_f32_16x16x32_bf16(a, blo, acc[mt], 0,0,0);
    }
  }
  #pragma unroll
  for (int mt = 0; mt < 2; ++mt){
    int c0 = wv*32 + mt*16 + lg*4;
    float4 bb = *(const float4*)(bc + c0);
    float4 ov;
    ov.x = acc[mt][0]+bb.x; ov.y = acc[mt][1]+bb.y; ov.z = acc[mt][2]+bb.z; ov.w = acc[mt][3]+bb.w;
    *(float4*)(o + (size_t)node*CC + c0) = ov;
    float vv[4] = {ov.x, ov.y, ov.z, ov.w};
    #pragma unroll
    for (int r = 0; r < 4; ++r){
      float a = vv[r], b = vv[r]*vv[r];
      a += __shfl_xor(a, 1); b += __shfl_xor(b, 1);
      a += __shfl_xor(a, 2); b += __shfl_xor(b, 2);
      a += __shfl_xor(a, 4); b += __shfl_xor(b, 4);
      a += __shfl_xor(a, 8); b += __shfl_xor(b, 8);
      if (lr == 0){ atomicAdd(&bns[c0+r], a); atomicAdd(&bns[CC+c0+r], b); }
    }
  }
}

// ---------------- BN(inline stats) + SiLU ----------------
__global__ void k_bnsilu(const float* __restrict__ o, const float* __restrict__ bns,
                         const float* __restrict__ g, const float* __restrict__ b,
                         float* __restrict__ h, unsigned short* __restrict__ h_bf){
  int i = blockIdx.x*256 + threadIdx.x;
  if (i < NN*CC){
    int c = i & 127;
    float mu = bns[c] * (1.0f/NN);
    float inv = rsqrtf(bns[CC+c] * (1.0f/NN) - mu*mu + 1e-5f);
    float z = (o[i] - mu) * inv * g[c] + b[c];
    float hv = siluf(z);
    h[i] = hv;
    h_bf[i] = f2bf(hv);
  }
}

__global__ void k_pool(const float* __restrict__ h, const int* __restrict__ batch,
                       float* __restrict__ pooled, float* __restrict__ counts){
  int i = blockIdx.x*256 + threadIdx.x;
  if (i < NN*CC){
    int n = i >> 7, c = i & 127;
    int g = batch[n];
    atomicAdd(&pooled[g*CC + c], h[i]);
    if (c == 0) atomicAdd(&counts[g], 1.0f);
  }
}

__global__ __launch_bounds__(128)
void k_final(const float* __restrict__ pooled, const float* __restrict__ counts,
             const float* __restrict__ Wfc, const float* __restrict__ bfc,
             float* __restrict__ out){
  __shared__ float psh[CC];
  int g = blockIdx.x; int t = threadIdx.x;
  float rc = 1.0f / fmaxf(counts[g], 1.0f);
  psh[t] = pooled[g*CC + t] * rc;
  __syncthreads();
  float acc = 0.f;
  for (int c = 0; c < CC; ++c) acc += psh[c] * Wfc[c*CC + t];
  out[g*CC + t] = siluf(acc + bfc[t]);
}

extern "C" void kernel_launch(void* const* d_in, const int* in_sizes, int n_in,
                              void* d_out, int out_size, void* d_ws, size_t ws_size,
                              hipStream_t stream){
  const float* x      = (const float*)d_in[0];
  const float* ea     = (const float*)d_in[1];
  const int*   ei     = (const int*)d_in[2];
  const int*   batch  = (const int*)d_in[3];
  const float* W_atom = (const float*)d_in[4];  const float* b_atom = (const float*)d_in[5];
  const float* W_rbf1 = (const float*)d_in[6];  const float* b_rbf1 = (const float*)d_in[7];
  const float* W_rbf2 = (const float*)d_in[8];  const float* b_rbf2 = (const float*)d_in[9];
  const float* Wq     = (const float*)d_in[10]; const float* bq     = (const float*)d_in[11];
  const float* Wk     = (const float*)d_in[12]; const float* bk     = (const float*)d_in[13];
  const float* Wv     = (const float*)d_in[14]; const float* bv     = (const float*)d_in[15];
  const float* We     = (const float*)d_in[16];
  const float* Wc     = (const float*)d_in[17]; const float* bc     = (const float*)d_in[18];
  const float* Wm     = (const float*)d_in[19]; const float* bm     = (const float*)d_in[20];
  const float* Wmsg   = (const float*)d_in[21]; const float* bmsg   = (const float*)d_in[22];
  const float* lnAg   = (const float*)d_in[23]; const float* lnAb   = (const float*)d_in[24];
  const float* lnMg   = (const float*)d_in[25]; const float* lnMb   = (const float*)d_in[26];
  const float* bng    = (const float*)d_in[27]; const float* bnb    = (const float*)d_in[28];
  const float* Wfc    = (const float*)d_in[29]; const float* bfc    = (const float*)d_in[30];

  float* ws = (float*)d_ws;
  size_t off = 0;
  auto alloc = [&](size_t n){ float* p = ws + off; off += n; return p; };
  float* h      = alloc((size_t)NN*CC);
  float* o      = alloc((size_t)NN*CC);
  float* agg    = alloc((size_t)NN*HD);
  float* bns    = alloc(2*CC);             // adjacent to agg: single memset covers both
  unsigned short* h_bf  = (unsigned short*)alloc((size_t)NN*CC/2);
  unsigned short* qb_bf = (unsigned short*)alloc((size_t)NN*HD/2);
  unsigned short* kb_bf = (unsigned short*)alloc((size_t)NN*HD/2);
  unsigned short* vb_bf = (unsigned short*)alloc((size_t)NN*HD/2);
  unsigned short* Pvi   = (unsigned short*)alloc((size_t)NN*HC3/2);
  unsigned short* Pvj   = (unsigned short*)alloc((size_t)NN*HC3/2);
  unsigned short* efs_bf= (unsigned short*)alloc((size_t)NE*CC/2);
  unsigned short* WeA   = (unsigned short*)alloc((size_t)NL*NH*CC*CC/2);
  unsigned short* WfA   = (unsigned short*)alloc((size_t)NL*NH*C3*CC/2);
  unsigned short* WvA   = (unsigned short*)alloc((size_t)NL*768*CC/2);
  unsigned short* WgA   = (unsigned short*)alloc((size_t)NL*CC*C3/2);
  unsigned short* WqkvA = (unsigned short*)alloc((size_t)NL*1536*CC/2);
  unsigned short* WcA   = (unsigned short*)alloc((size_t)NL*CC*HD/2);
  int* cnt    = (int*)alloc(8192);
  int* offs   = (int*)alloc(NN);
  int* cursor = (int*)alloc(NN);
  int* sperm  = (int*)alloc(NE);
  int* iperm  = (int*)alloc(NE);
  int* ssrc   = (int*)alloc(NE);
  int* sdst   = (int*)alloc(NE);
  float* pooled = alloc((size_t)NG*CC);
  float* counts = alloc(NG);

  if (off * sizeof(float) > ws_size){
    hipMemsetAsync(d_out, 0x7F, (size_t)out_size*sizeof(float), stream);
    return;
  }

  const int* srcI = ei;
  const int* dstI = ei + NE;

  // ---- sort edges by dst (once; reused by all 5 layers) ----
  hipMemsetAsync(cnt, 0, 8192*sizeof(int), stream);
  k_hist<<<(NE+255)/256, 256, 0, stream>>>(dstI, cnt);
  k_scan<<<1, 1024, 0, stream>>>(cnt, offs, cursor);
  k_scatter<<<(NE+255)/256, 256, 0, stream>>>(dstI, cursor, sperm, iperm);
  k_meta<<<(NE+255)/256, 256, 0, stream>>>(sperm, srcI, dstI, ssrc, sdst);

  // ---- weight prep ----
  k_prep_we<<<(NL*NH*CC*CC + 255)/256, 256, 0, stream>>>(We, WeA);
  k_prep_wv<<<(NL*768*CC + 255)/256, 256, 0, stream>>>(Wm, WvA);
  k_prep_wg<<<(NL*CC*C3 + 255)/256, 256, 0, stream>>>(Wmsg, WgA);
  k_prep_wf<<<NL*NH*C3, 128, 0, stream>>>(We, Wm, WfA);
  k_prep_wqkv<<<(NL*1536*CC + 255)/256, 256, 0, stream>>>(Wq, Wk, Wv, WqkvA);
  k_prep_wc<<<(NL*CC*HD + 255)/256, 256, 0, stream>>>(Wc, WcA);

  k_stem<<<NN/8, 128, 0, stream>>>(x, W_atom, b_atom, h, h_bf);
  k_rbf<<<NE/8, 128, 0, stream>>>(ea, W_rbf1, b_rbf1, W_rbf2, b_rbf2, iperm, efs_bf);

  for (int l = 0; l < NL; ++l){
    const float* bq_l   = bq   + (size_t)l*HD;
    const float* bk_l   = bk   + (size_t)l*HD;
    const float* bv_l   = bv   + (size_t)l*HD;
    const float* bc_l   = bc   + (size_t)l*CC;
    const float* bm_l   = bm   + (size_t)l*C3;
    const float* bmsg_l = bmsg + (size_t)l*CC;
    const float* lnAg_l = lnAg + (size_t)l*C3;      const float* lnAb_l = lnAb + (size_t)l*C3;
    const float* lnMg_l = lnMg + (size_t)l*CC;      const float* lnMb_l = lnMb + (size_t)l*CC;
    const float* bng_l  = bng  + (size_t)l*CC;      const float* bnb_l  = bnb  + (size_t)l*CC;
    const unsigned short* WeA_l = WeA + (size_t)l*NH*CC*CC;
    const unsigned short* WfA_l = WfA + (size_t)l*NH*C3*CC;
    const unsigned short* WvA_l = WvA + (size_t)l*768*CC;
    const unsigned short* WgA_l = WgA + (size_t)l*CC*C3;
    const unsigned short* WqkvA_l = WqkvA + (size_t)l*1536*CC;
    const unsigned short* WcA_l = WcA + (size_t)l*CC*HD;

    k_qkv_mfma<<<dim3(NN/32, 3), 256, 0, stream>>>(h_bf, WqkvA_l, bq_l, bk_l, bv_l,
                                                   qb_bf, kb_bf, vb_bf);
    k_pv_mfma<<<dim3(NN/32, NH), 256, 0, stream>>>(vb_bf, WvA_l, bm_l, Pvi, Pvj);

    hipMemsetAsync(agg, 0, ((size_t)NN*HD + 2*CC)*sizeof(float), stream);  // agg + bns

    k_edge_mfma<<<dim3(NEB, NH), 256, 0, stream>>>(efs_bf, qb_bf, kb_bf, Pvi, Pvj, ssrc, sdst,
                                                   WeA_l, WfA_l, WgA_l,
                                                   lnAg_l, lnAb_l, lnMg_l, lnMb_l, bmsg_l, agg);

    k_oc<<<NN/TE, 256, 0, stream>>>(agg, WcA_l, bc_l, o, bns);
    k_bnsilu<<<(NN*CC+255)/256, 256, 0, stream>>>(o, bns, bng_l, bnb_l, h, h_bf);
  }

  hipMemsetAsync(pooled, 0, ((size_t)NG*CC + NG)*sizeof(float), stream);
  k_pool<<<(NN*CC+255)/256, 256, 0, stream>>>(h, batch, pooled, counts);
  k_final<<<NG, 128, 0, stream>>>(pooled, counts, Wfc, bfc, (float*)d_out);
}